// Round 2
// baseline (233.021 us; speedup 1.0000x reference)
//
#include <hip/hip_runtime.h>
#include <hip/hip_bf16.h>

// LayerNorm over last dim W=256 for (B=8, C=128, H=128, W=256) fp32,
// then per-channel affine: out = (x - mean)/sqrt(var+eps) * gain[c] + bias[c].
//
// R2 structure: 8 rows per wave, 8 lanes per row, 32 floats (8x float4) per
// lane. 8 independent global loads in flight per wave (MLP=8, 8 KB/wave) vs
// 1 in R1; cross-lane reduction is 3 dependent shfl_xor steps (1,2,4) vs 6.
// Memory-bound target: 268 MB total traffic, ~43 us at 6.3 TB/s.

#define W_DIM 256
#define C_DIM 128
#define EPS 1e-8f

__global__ __launch_bounds__(256) void tLNv2_kernel(
    const float* __restrict__ inp,
    const float* __restrict__ gain,
    const float* __restrict__ bias,
    float* __restrict__ out)
{
    const int lane = threadIdx.x & 63;
    const int wave = threadIdx.x >> 6;
    const int l = lane & 7;   // lane within row (8 lanes/row)
    const int r = lane >> 3;  // row within this wave's group of 8

    // Each block (4 waves) covers 32 rows.
    const long long row = (long long)blockIdx.x * 32 + wave * 8 + r;
    const float4* __restrict__ in4 = (const float4*)(inp + row * W_DIM);

    // 8 independent float4 loads: chunk k covers floats [k*32, k*32+32) of the
    // row; lane l takes floats [k*32 + l*4, +4). Contiguous 128 B per 8 lanes.
    float4 v[8];
    #pragma unroll
    for (int k = 0; k < 8; ++k)
        v[k] = in4[k * 8 + l];

    // In-register tree accumulation (full ILP), then 3-step cross-lane reduce.
    float s = 0.0f, sq = 0.0f;
    #pragma unroll
    for (int k = 0; k < 8; ++k) {
        s  += (v[k].x + v[k].y) + (v[k].z + v[k].w);
        sq += (v[k].x * v[k].x + v[k].y * v[k].y)
            + (v[k].z * v[k].z + v[k].w * v[k].w);
    }
    #pragma unroll
    for (int off = 1; off < 8; off <<= 1) {
        s  += __shfl_xor(s,  off, 64);
        sq += __shfl_xor(sq, off, 64);
    }

    const float mean = s * (1.0f / (float)W_DIM);
    const float var  = sq * (1.0f / (float)W_DIM) - mean * mean;
    const float rstd = rsqrtf(var + EPS);

    // row = b*C*H + c*H + h ; H=128, C=128 -> c = (row >> 7) & 127
    const int c = (int)((row >> 7) & (C_DIM - 1));
    const float g = gain[c] * rstd;          // fold: out = v*g' + b'
    const float b = bias[c] - mean * g;

    float4* __restrict__ out4 = (float4*)(out + row * W_DIM);
    #pragma unroll
    for (int k = 0; k < 8; ++k) {
        float4 o;
        o.x = v[k].x * g + b;
        o.y = v[k].y * g + b;
        o.z = v[k].z * g + b;
        o.w = v[k].w * g + b;
        out4[k * 8 + l] = o;
    }
}

extern "C" void kernel_launch(void* const* d_in, const int* in_sizes, int n_in,
                              void* d_out, int out_size, void* d_ws, size_t ws_size,
                              hipStream_t stream)
{
    const float* inp  = (const float*)d_in[0];
    const float* gain = (const float*)d_in[1];
    const float* bias = (const float*)d_in[2];
    float* out = (float*)d_out;

    const long long rows = (long long)in_sizes[0] / W_DIM;  // 131072
    const int blocks = (int)(rows / 32);                    // 32 rows per block

    tLNv2_kernel<<<blocks, 256, 0, stream>>>(inp, gain, bias, out);
}

// Round 3
// 230.881 us; speedup vs baseline: 1.0093x; 1.0093x over previous
//
#include <hip/hip_runtime.h>
#include <hip/hip_bf16.h>

// LayerNorm over last dim W=256 for (B=8, C=128, H=128, W=256) fp32,
// then per-channel affine: out = (x - mean)/sqrt(var+eps) * gain[c] + bias[c].
//
// R3: one full row per wave-load (64 lanes x float4 = contiguous 1 KiB per
// instruction, perfect coalescing like R1), but 4 rows per wave to get MLP=4
// on the global loads and ILP=4 across the butterfly-reduction chains
// (R1 was latency-bound: MLP=1 + one serialized 6-step shfl chain;
//  R2's 8-lanes/row layout broke store coalescing and regressed).

#define W_DIM 256
#define C_DIM 128
#define ROWS_PER_WAVE 4
#define EPS 1e-8f

__global__ __launch_bounds__(256) void tLNv2_kernel(
    const float* __restrict__ inp,
    const float* __restrict__ gain,
    const float* __restrict__ bias,
    float* __restrict__ out)
{
    const int lane = threadIdx.x & 63;
    const int wave = threadIdx.x >> 6;

    // Block = 4 waves; each wave owns 4 consecutive rows -> 16 rows/block.
    const long long row0 = ((long long)blockIdx.x * 4 + wave) * ROWS_PER_WAVE;
    const float4* __restrict__ in4 = (const float4*)(inp + row0 * W_DIM);

    // 4 independent, fully-coalesced loads (each: 64 lanes x 16 B = 1 KiB).
    float4 v[ROWS_PER_WAVE];
    #pragma unroll
    for (int j = 0; j < ROWS_PER_WAVE; ++j)
        v[j] = in4[j * 64 + lane];

    // Per-row partial sums in-register (full ILP).
    float s[ROWS_PER_WAVE], sq[ROWS_PER_WAVE];
    #pragma unroll
    for (int j = 0; j < ROWS_PER_WAVE; ++j) {
        s[j]  = (v[j].x + v[j].y) + (v[j].z + v[j].w);
        sq[j] = (v[j].x * v[j].x + v[j].y * v[j].y)
              + (v[j].z * v[j].z + v[j].w * v[j].w);
    }

    // 6-step butterfly, 4 independent chains interleaved (8 ds ops per step,
    // no serial dependency between rows -> shfl latency hidden).
    #pragma unroll
    for (int off = 1; off < 64; off <<= 1) {
        #pragma unroll
        for (int j = 0; j < ROWS_PER_WAVE; ++j) {
            s[j]  += __shfl_xor(s[j],  off, 64);
            sq[j] += __shfl_xor(sq[j], off, 64);
        }
    }

    // Epilogue: fold affine into one FMA per element; coalesced 1 KiB stores.
    float4* __restrict__ out4 = (float4*)(out + row0 * W_DIM);
    #pragma unroll
    for (int j = 0; j < ROWS_PER_WAVE; ++j) {
        const float mean = s[j] * (1.0f / (float)W_DIM);
        const float var  = sq[j] * (1.0f / (float)W_DIM) - mean * mean;
        const float rstd = rsqrtf(var + EPS);

        // row = b*C*H + c*H + h ; H=128, C=128 -> c = (row >> 7) & 127
        const int c = (int)(((row0 + j) >> 7) & (C_DIM - 1));
        const float g = gain[c] * rstd;
        const float b = bias[c] - mean * g;

        float4 o;
        o.x = v[j].x * g + b;
        o.y = v[j].y * g + b;
        o.z = v[j].z * g + b;
        o.w = v[j].w * g + b;
        out4[j * 64 + lane] = o;
    }
}

extern "C" void kernel_launch(void* const* d_in, const int* in_sizes, int n_in,
                              void* d_out, int out_size, void* d_ws, size_t ws_size,
                              hipStream_t stream)
{
    const float* inp  = (const float*)d_in[0];
    const float* gain = (const float*)d_in[1];
    const float* bias = (const float*)d_in[2];
    float* out = (float*)d_out;

    const long long rows = (long long)in_sizes[0] / W_DIM;      // 131072
    const int blocks = (int)(rows / (4 * ROWS_PER_WAVE));       // 16 rows/block

    tLNv2_kernel<<<blocks, 256, 0, stream>>>(inp, gain, bias, out);
}